// Round 2
// baseline (1136.228 us; speedup 1.0000x reference)
//
#include <hip/hip_runtime.h>
#include <stdint.h>

// ---------------------------------------------------------------------------
// MD5Surrogate: 64-round scan of 3-layer MLP (22->256->256->16), B=16384.
// fp32 in/out. R12: keep 512x512 geometry (8 waves, NG=2, TT=2, 2 blocks/CU).
// Changes vs R11:
//  (1) L3 distributed: wave0 -> group0, wave1 -> group1, plus a 3rd barrier.
//      Removes the 8-way-redundant L3 (16 hB reads + 16 MFMA + split2 per
//      wave -> per-CU LDS reads 576->336, MFMA 896->352 per round).
//  (2) Weight prefetch: next round's a1/bb1/bb2 + tt=0 half of a2 are loaded
//      into regs during the L3 phase (latency hides under L3+barrier+L1);
//      tt=1 a2 half loads at L2-phase start before the Bf ds_reads.
//  (3) a3/bb3 loads gated to waves 0,1; next-word scatter on wave 2 only.
// Structure otherwise: bf16 hi/lo x, A&S 7.1.25 gelu, bias-in-accumulator.
// ---------------------------------------------------------------------------

using bf16x8   = __attribute__((ext_vector_type(8))) __bf16;
using floatx4  = __attribute__((ext_vector_type(4))) float;
using ushort4v = __attribute__((ext_vector_type(4))) unsigned short;

__constant__ int c_sched[64] = {
  0,1,2,3,4,5,6,7,8,9,10,11,12,13,14,15,
  1,6,11,0,5,10,15,4,9,14,3,8,13,2,7,12,
  5,8,11,14,1,4,7,10,13,0,3,6,9,12,15,2,
  0,7,14,5,12,3,10,1,8,15,6,13,4,11,2,9
};
__constant__ float c_shift[64] = {
  7,12,17,22,7,12,17,22,7,12,17,22,7,12,17,22,
  5,9,14,20,5,9,14,20,5,9,14,20,5,9,14,20,
  4,11,16,23,4,11,16,23,4,11,16,23,4,11,16,23,
  6,10,15,21,6,10,15,21,6,10,15,21,6,10,15,21
};

__device__ __forceinline__ unsigned short bfbits(__bf16 b) {
  union { __bf16 b; unsigned short u; } v; v.b = b; return v.u;
}
// gelu via A&S 7.1.25 (|eps|<=2.5e-5), constants folded, exp2-scaled
__device__ __forceinline__ float gelu_f(float x) {
  float ax = fabsf(x);
  float t  = __builtin_amdgcn_rcpf(__builtin_fmaf(0.33270222f, ax, 1.0f));
  float e  = __builtin_amdgcn_exp2f(x * x * -0.72134752f);
  float poly = t * __builtin_fmaf(t, __builtin_fmaf(t, 0.7478556f, -0.0958798f),
                                  0.3480242f);
  float er = __builtin_fmaf(-poly, e, 1.0f);
  er = copysignf(er, x);
  float hx = 0.5f * x;
  return __builtin_fmaf(hx, er, hx);
}
__device__ __forceinline__ floatx4 mfma16(bf16x8 a, bf16x8 b, floatx4 c) {
  return __builtin_amdgcn_mfma_f32_16x16x32_bf16(a, b, c, 0, 0, 0);
}
struct BfPair { unsigned short h, l; };
__device__ __forceinline__ BfPair split2(float s) {
  __bf16 hb = (__bf16)s;
  __bf16 lb = (__bf16)(s - (float)hb);
  BfPair p; p.h = bfbits(hb); p.l = bfbits(lb); return p;
}

// ---------------------------------------------------------------------------
// Packed-weight layout: fragment = 64 lanes x 8 bf16. A[m][k]: m=lane&15,
// k=8*(lane>>4)+j.  P1 (r*16+t): W1[r][k][16t+m] (k>=22 -> 0)
//                   P2 ((r*16+t)*8+c): W2[r][32c+k'][16t+m]
//                   P3 (r*8+c): W3[r][32c+k'][m]
// ---------------------------------------------------------------------------
#define N1G (64*16*64)
#define N2G (64*16*8*64)
#define N3G (64*8*64)

__global__ void pack_w(const float* __restrict__ W1,
                       const float* __restrict__ W2,
                       const float* __restrict__ W3,
                       unsigned short* __restrict__ P) {
  int gid = blockIdx.x * blockDim.x + threadIdx.x;
  if (gid >= N1G + N2G + N3G) return;
  unsigned short v[8];
  unsigned short* dst;
  if (gid < N1G) {
    int lane = gid & 63, t = (gid >> 6) & 15, r = gid >> 10;
    int qq = lane >> 4, mm = lane & 15;
    #pragma unroll
    for (int j = 0; j < 8; ++j) {
      int k = 8*qq + j;
      v[j] = (k < 22) ? bfbits((__bf16)W1[(r*22 + k)*256 + 16*t + mm]) : (unsigned short)0;
    }
    dst = P + (size_t)gid * 8;
  } else if (gid < N1G + N2G) {
    int g = gid - N1G;
    int lane = g & 63, c = (g >> 6) & 7, t = (g >> 9) & 15, r = g >> 13;
    int qq = lane >> 4, mm = lane & 15;
    #pragma unroll
    for (int j = 0; j < 8; ++j) {
      int k = 32*c + 8*qq + j;
      v[j] = bfbits((__bf16)W2[((size_t)r*256 + k)*256 + 16*t + mm]);
    }
    dst = P + (size_t)(N1G + g) * 8;
  } else {
    int g = gid - N1G - N2G;
    int lane = g & 63, c = (g >> 6) & 7, r = g >> 9;
    int qq = lane >> 4, mm = lane & 15;
    #pragma unroll
    for (int j = 0; j < 8; ++j) {
      int k = 32*c + 8*qq + j;
      v[j] = bfbits((__bf16)W3[(r*256 + k)*16 + mm]);
    }
    dst = P + (size_t)(N1G + N2G + g) * 8;
  }
  ushort4v lo = { v[0],v[1],v[2],v[3] }, hi = { v[4],v[5],v[6],v[7] };
  *(ushort4v*)dst = lo;
  *(ushort4v*)(dst + 4) = hi;
}

// ---------------------------------------------------------------------------
#define NG  2    // row-groups per block (32 rows/block)
#define TT  2    // feature sub-tiles per wave (8 waves x 32 features = 256)
#define SXW 36   // x row stride (ushorts)
#define SH 264   // h row stride
#define SM 66    // msg row stride

__global__ __launch_bounds__(512, 4) void md5_main(
    const float* __restrict__ msg,   // (16384,64)
    const float* __restrict__ st0,   // (16384,16)
    const float* __restrict__ b1,    // (64,256)
    const float* __restrict__ b2,    // (64,256)
    const float* __restrict__ b3,    // (64,16)
    const unsigned short* __restrict__ P,
    float* __restrict__ out)         // (16384,16)
{
  __shared__ unsigned short xh[NG][16][SXW], xl[NG][16][SXW];
  __shared__ unsigned short hA[NG][16][SH], hB[NG][16][SH];
  __shared__ unsigned short msgb[NG*16][SM], msgl[NG*16][SM];

  const int tid  = threadIdx.x;
  const int wv   = tid >> 6;        // 0..7
  const int lane = tid & 63;
  const int q    = lane >> 4;
  const int ln   = lane & 15;
  const int row0 = blockIdx.x * (NG*16);

  const unsigned short* P1 = P;
  const unsigned short* P2 = P + (size_t)N1G * 8;
  const unsigned short* P3 = P + (size_t)(N1G + N2G) * 8;

  // zero x buffers once (pad cols 22..35 must stay 0 forever)
  for (int i = tid; i < NG*16*SXW; i += 512) {
    (&xh[0][0][0])[i] = 0; (&xl[0][0][0])[i] = 0;
  }
  // msg preload (shared, hi/lo): 32 rows x 64 = 2048 elems / 512 thr = 4 each
  {
    int idx = tid * 4, rr = idx >> 6, cc = idx & 63;
    floatx4 v0 = *(const floatx4*)(msg + (size_t)(row0 + rr)*64 + cc);
    #pragma unroll
    for (int j = 0; j < 4; ++j) {
      BfPair p0 = split2(v0[j]);
      msgb[rr][cc + j] = p0.h;  msgl[rr][cc + j] = p0.l;
    }
  }
  // init state: one wave suffices (ordered by the barrier below)
  if (wv == 0) {
    #pragma unroll
    for (int g = 0; g < NG; ++g) {
      floatx4 v = *(const floatx4*)(st0 + (size_t)(row0 + g*16 + ln)*16 + 4*q);
      ushort4v h4, l4;
      #pragma unroll
      for (int e = 0; e < 4; ++e) { BfPair p = split2(v[e]); h4[e] = p.h; l4[e] = p.l; }
      *(ushort4v*)&xh[g][ln][4*q] = h4;
      *(ushort4v*)&xl[g][ln][4*q] = l4;
    }
  }
  __syncthreads();   // msgb/msgl + state + zero-pads ready
  // round-0 word+rinfo: every wave writes the full (identical) set so its own
  // L1 reads are covered without another barrier
  if (lane < NG*16) {
    int g = lane >> 4, n = lane & 15, rrow = lane;
    int s = c_sched[0];
    BfPair i1p = split2(c_shift[0] / 25.0f);
    #pragma unroll
    for (int j = 0; j < 4; ++j) {
      xh[g][n][16+j] = msgb[rrow][4*s+j];
      xl[g][n][16+j] = msgl[rrow][4*s+j];
    }
    xh[g][n][20] = 0;     xl[g][n][20] = 0;   // round 0: i/64 = 0
    xh[g][n][21] = i1p.h; xl[g][n][21] = i1p.l;
  }

  // ---- prefetched weight regs for the CURRENT round r ----
  bf16x8  a1c[TT];  floatx4 bb1c[TT];
  bf16x8  a2c[8];   floatx4 bb2c[TT];   // a2c = tt=0 half of a2
  {
    const unsigned short* p1 = P1 + ((size_t)(TT*wv)*64 + lane)*8;
    #pragma unroll
    for (int tt = 0; tt < TT; ++tt) {
      a1c[tt]  = *(const bf16x8*)(p1 + (size_t)tt*512);
      bb1c[tt] = *(const floatx4*)(b1 + (TT*wv + tt)*16 + 4*q);
      bb2c[tt] = *(const floatx4*)(b2 + (TT*wv + tt)*16 + 4*q);
    }
    const unsigned short* p2 = P2 + ((size_t)((TT*wv)*8)*64 + lane)*8;
    #pragma unroll
    for (int c = 0; c < 8; ++c) a2c[c] = *(const bf16x8*)(p2 + (size_t)c*512);
  }

  #pragma unroll 1
  for (int r = 0; r < 64; ++r) {
    // -------- Layer 1: x @ W1 -> h1 (own 32-feature slice, both groups) ----
    bf16x8 bxh[NG], bxl[NG];
    #pragma unroll
    for (int g = 0; g < NG; ++g) {
      bxh[g] = *(const bf16x8*)&xh[g][ln][8*q];
      bxl[g] = *(const bf16x8*)&xl[g][ln][8*q];
    }
    #pragma unroll
    for (int tt = 0; tt < TT; ++tt) {
      int f0 = (TT*wv + tt)*16 + 4*q;
      #pragma unroll
      for (int g = 0; g < NG; ++g) {
        floatx4 acc = bb1c[tt];
        acc = mfma16(a1c[tt], bxl[g], acc);
        acc = mfma16(a1c[tt], bxh[g], acc);
        ushort4v h4;
        #pragma unroll
        for (int e = 0; e < 4; ++e) h4[e] = bfbits((__bf16)gelu_f(acc[e]));
        *(ushort4v*)&hA[g][ln][f0] = h4;
      }
    }
    __syncthreads();                       // (B) h1 ready; hB free

    // -------- Layer 2: h1 @ W2 -> h2 (own slice, both groups) --------
    // a3/bb3 only on the two L3 waves; latency hides under L2 compute.
    bf16x8 a3[8]; floatx4 bb3;
    if (wv < 2) {
      const unsigned short* p3 = P3 + ((size_t)(r*8)*64 + lane)*8;
      #pragma unroll
      for (int c = 0; c < 8; ++c) a3[c] = *(const bf16x8*)(p3 + (size_t)c*512);
      bb3 = *(const floatx4*)(b3 + r*16 + 4*q);
    }
    // tt=1 half of a2: issue before the Bf ds_reads so latency hides there
    bf16x8 a2b[8];
    {
      const unsigned short* p2 = P2 + ((size_t)((r*16 + TT*wv)*8)*64 + lane)*8;
      #pragma unroll
      for (int c = 0; c < 8; ++c)
        a2b[c] = *(const bf16x8*)(p2 + (size_t)(8 + c)*512);
    }
    bf16x8 Bf[NG][8];
    #pragma unroll
    for (int g = 0; g < NG; ++g)
      #pragma unroll
      for (int c = 0; c < 8; ++c) Bf[g][c] = *(const bf16x8*)&hA[g][ln][32*c + 8*q];

    // tt=0 uses prefetched a2c; tt=1 uses a2b
    #pragma unroll
    for (int tt = 0; tt < TT; ++tt) {
      int f0 = (TT*wv + tt)*16 + 4*q;
      #pragma unroll
      for (int g = 0; g < NG; ++g) {
        floatx4 acc = bb2c[tt];
        #pragma unroll
        for (int c = 0; c < 8; ++c)
          acc = mfma16(tt == 0 ? a2c[c] : a2b[c], Bf[g][c], acc);
        ushort4v h4;
        #pragma unroll
        for (int e = 0; e < 4; ++e) h4[e] = bfbits((__bf16)gelu_f(acc[e]));
        *(ushort4v*)&hB[g][ln][f0] = h4;
      }
    }
    __syncthreads();                       // (C) h2 ready

    // -------- prefetch next round's weights (overlaps L3 + barrier D + L1) --
    if (r < 63) {
      const unsigned short* p1n = P1 + ((size_t)((r+1)*16 + TT*wv)*64 + lane)*8;
      #pragma unroll
      for (int tt = 0; tt < TT; ++tt) {
        a1c[tt]  = *(const bf16x8*)(p1n + (size_t)tt*512);
        bb1c[tt] = *(const floatx4*)(b1 + (r+1)*256 + (TT*wv + tt)*16 + 4*q);
        bb2c[tt] = *(const floatx4*)(b2 + (r+1)*256 + (TT*wv + tt)*16 + 4*q);
      }
      const unsigned short* p2n = P2 + ((size_t)(((r+1)*16 + TT*wv)*8)*64 + lane)*8;
      #pragma unroll
      for (int c = 0; c < 8; ++c) a2c[c] = *(const bf16x8*)(p2n + (size_t)c*512);
    }

    // -------- Layer 3 (distributed: wave g computes group g) --------
    if (wv < 2) {
      const int g = wv;
      floatx4 s = bb3;
      #pragma unroll
      for (int c = 0; c < 8; ++c) {
        bf16x8 bh = *(const bf16x8*)&hB[g][ln][32*c + 8*q];
        s = mfma16(a3[c], bh, s);
      }
      if (r == 63) {
        *(floatx4*)(out + (size_t)(row0 + g*16 + ln)*16 + 4*q) = s;
      } else {
        ushort4v h4, l4;
        #pragma unroll
        for (int e = 0; e < 4; ++e) { BfPair p = split2(s[e]); h4[e] = p.h; l4[e] = p.l; }
        *(ushort4v*)&xh[g][ln][4*q] = h4;
        *(ushort4v*)&xl[g][ln][4*q] = l4;
      }
    }
    // word + rinfo for next round: wave 2 only (published by barrier D)
    if (wv == 2 && lane < NG*16 && r < 63) {
      int g = lane >> 4, n = lane & 15, rrow = lane;
      int sc = c_sched[r+1];
      float i0 = (float)(r+1) * 0.015625f;   // exact in bf16
      BfPair i1p = split2(c_shift[r+1] / 25.0f);
      #pragma unroll
      for (int j = 0; j < 4; ++j) {
        xh[g][n][16+j] = msgb[rrow][4*sc+j];
        xl[g][n][16+j] = msgl[rrow][4*sc+j];
      }
      xh[g][n][20] = bfbits((__bf16)i0); xl[g][n][20] = 0;
      xh[g][n][21] = i1p.h;              xl[g][n][21] = i1p.l;
    }
    if (r < 63) __syncthreads();           // (D) x ready for next L1
  }
}

// ---------------------------------------------------------------------------
extern "C" void kernel_launch(void* const* d_in, const int* in_sizes, int n_in,
                              void* d_out, int out_size, void* d_ws, size_t ws_size,
                              hipStream_t stream) {
  const float* msg = (const float*)d_in[0];
  const float* st0 = (const float*)d_in[1];
  const float* W1  = (const float*)d_in[2];
  const float* b1  = (const float*)d_in[3];
  const float* W2  = (const float*)d_in[4];
  const float* b2  = (const float*)d_in[5];
  const float* W3  = (const float*)d_in[6];
  const float* b3  = (const float*)d_in[7];
  float* out = (float*)d_out;
  (void)in_sizes; (void)n_in; (void)out_size; (void)ws_size;

  unsigned short* P = (unsigned short*)d_ws;
  const int totalGroups = N1G + N2G + N3G;   // 622592
  pack_w<<<(totalGroups + 255) / 256, 256, 0, stream>>>(W1, W2, W3, P);
  md5_main<<<512, 512, 0, stream>>>(msg, st0, b1, b2, b3, P, out);
}

// Round 3
// 590.102 us; speedup vs baseline: 1.9255x; 1.9255x over previous
//
#include <hip/hip_runtime.h>
#include <stdint.h>

// ---------------------------------------------------------------------------
// MD5Surrogate: 64-round scan of 3-layer MLP (22->256->256->16), B=16384.
// fp32 in/out. R13 = R11 structure (512 thr, 8 waves, NG=2, TT=2, 2 blk/CU,
// NO cross-round register prefetch -- R12's prefetch spilled to scratch:
// WRITE_SIZE 1MB -> 2.4GB) + distributed L3:
//  (1) L3 computed by wave0 (group0) / wave1 (group1) only; a3/bb3 loads
//      gated to those waves. Removes the 8-way-redundant L3 of R11
//      (-21% MFMA/CU, -39% b128 LDS reads/CU, -6 waves of split2 VALU).
//  (2) next-round word+rinfo scatter on wave 2 only.
//  (3) barrier D at end of round publishes x for all waves' next L1.
// Structure otherwise: bf16 hi/lo x, shared hA/hB staging, A&S 7.1.25 gelu,
// bias-in-accumulator, a2 loaded per-tt inside the loop (compiler-scheduled).
// ---------------------------------------------------------------------------

using bf16x8   = __attribute__((ext_vector_type(8))) __bf16;
using floatx4  = __attribute__((ext_vector_type(4))) float;
using ushort4v = __attribute__((ext_vector_type(4))) unsigned short;

__constant__ int c_sched[64] = {
  0,1,2,3,4,5,6,7,8,9,10,11,12,13,14,15,
  1,6,11,0,5,10,15,4,9,14,3,8,13,2,7,12,
  5,8,11,14,1,4,7,10,13,0,3,6,9,12,15,2,
  0,7,14,5,12,3,10,1,8,15,6,13,4,11,2,9
};
__constant__ float c_shift[64] = {
  7,12,17,22,7,12,17,22,7,12,17,22,7,12,17,22,
  5,9,14,20,5,9,14,20,5,9,14,20,5,9,14,20,
  4,11,16,23,4,11,16,23,4,11,16,23,4,11,16,23,
  6,10,15,21,6,10,15,21,6,10,15,21,6,10,15,21
};

__device__ __forceinline__ unsigned short bfbits(__bf16 b) {
  union { __bf16 b; unsigned short u; } v; v.b = b; return v.u;
}
// gelu via A&S 7.1.25 (|eps|<=2.5e-5), constants folded, exp2-scaled
__device__ __forceinline__ float gelu_f(float x) {
  float ax = fabsf(x);
  float t  = __builtin_amdgcn_rcpf(__builtin_fmaf(0.33270222f, ax, 1.0f));
  float e  = __builtin_amdgcn_exp2f(x * x * -0.72134752f);
  float poly = t * __builtin_fmaf(t, __builtin_fmaf(t, 0.7478556f, -0.0958798f),
                                  0.3480242f);
  float er = __builtin_fmaf(-poly, e, 1.0f);
  er = copysignf(er, x);
  float hx = 0.5f * x;
  return __builtin_fmaf(hx, er, hx);
}
__device__ __forceinline__ floatx4 mfma16(bf16x8 a, bf16x8 b, floatx4 c) {
  return __builtin_amdgcn_mfma_f32_16x16x32_bf16(a, b, c, 0, 0, 0);
}
struct BfPair { unsigned short h, l; };
__device__ __forceinline__ BfPair split2(float s) {
  __bf16 hb = (__bf16)s;
  __bf16 lb = (__bf16)(s - (float)hb);
  BfPair p; p.h = bfbits(hb); p.l = bfbits(lb); return p;
}

// ---------------------------------------------------------------------------
// Packed-weight layout: fragment = 64 lanes x 8 bf16. A[m][k]: m=lane&15,
// k=8*(lane>>4)+j.  P1 (r*16+t): W1[r][k][16t+m] (k>=22 -> 0)
//                   P2 ((r*16+t)*8+c): W2[r][32c+k'][16t+m]
//                   P3 (r*8+c): W3[r][32c+k'][m]
// ---------------------------------------------------------------------------
#define N1G (64*16*64)
#define N2G (64*16*8*64)
#define N3G (64*8*64)

__global__ void pack_w(const float* __restrict__ W1,
                       const float* __restrict__ W2,
                       const float* __restrict__ W3,
                       unsigned short* __restrict__ P) {
  int gid = blockIdx.x * blockDim.x + threadIdx.x;
  if (gid >= N1G + N2G + N3G) return;
  unsigned short v[8];
  unsigned short* dst;
  if (gid < N1G) {
    int lane = gid & 63, t = (gid >> 6) & 15, r = gid >> 10;
    int qq = lane >> 4, mm = lane & 15;
    #pragma unroll
    for (int j = 0; j < 8; ++j) {
      int k = 8*qq + j;
      v[j] = (k < 22) ? bfbits((__bf16)W1[(r*22 + k)*256 + 16*t + mm]) : (unsigned short)0;
    }
    dst = P + (size_t)gid * 8;
  } else if (gid < N1G + N2G) {
    int g = gid - N1G;
    int lane = g & 63, c = (g >> 6) & 7, t = (g >> 9) & 15, r = g >> 13;
    int qq = lane >> 4, mm = lane & 15;
    #pragma unroll
    for (int j = 0; j < 8; ++j) {
      int k = 32*c + 8*qq + j;
      v[j] = bfbits((__bf16)W2[((size_t)r*256 + k)*256 + 16*t + mm]);
    }
    dst = P + (size_t)(N1G + g) * 8;
  } else {
    int g = gid - N1G - N2G;
    int lane = g & 63, c = (g >> 6) & 7, r = g >> 9;
    int qq = lane >> 4, mm = lane & 15;
    #pragma unroll
    for (int j = 0; j < 8; ++j) {
      int k = 32*c + 8*qq + j;
      v[j] = bfbits((__bf16)W3[(r*256 + k)*16 + mm]);
    }
    dst = P + (size_t)(N1G + N2G + g) * 8;
  }
  ushort4v lo = { v[0],v[1],v[2],v[3] }, hi = { v[4],v[5],v[6],v[7] };
  *(ushort4v*)dst = lo;
  *(ushort4v*)(dst + 4) = hi;
}

// ---------------------------------------------------------------------------
#define NG  2    // row-groups per block (32 rows/block)
#define TT  2    // feature sub-tiles per wave (8 waves x 32 features = 256)
#define SXW 36   // x row stride (ushorts)
#define SH 264   // h row stride
#define SM 66    // msg row stride

__global__ __launch_bounds__(512, 4) void md5_main(
    const float* __restrict__ msg,   // (16384,64)
    const float* __restrict__ st0,   // (16384,16)
    const float* __restrict__ b1,    // (64,256)
    const float* __restrict__ b2,    // (64,256)
    const float* __restrict__ b3,    // (64,16)
    const unsigned short* __restrict__ P,
    float* __restrict__ out)         // (16384,16)
{
  __shared__ unsigned short xh[NG][16][SXW], xl[NG][16][SXW];
  __shared__ unsigned short hA[NG][16][SH], hB[NG][16][SH];
  __shared__ unsigned short msgb[NG*16][SM], msgl[NG*16][SM];

  const int tid  = threadIdx.x;
  const int wv   = tid >> 6;        // 0..7
  const int lane = tid & 63;
  const int q    = lane >> 4;
  const int ln   = lane & 15;
  const int row0 = blockIdx.x * (NG*16);

  const unsigned short* P1 = P;
  const unsigned short* P2 = P + (size_t)N1G * 8;
  const unsigned short* P3 = P + (size_t)(N1G + N2G) * 8;

  // zero x buffers once (pad cols 22..35 must stay 0 forever)
  for (int i = tid; i < NG*16*SXW; i += 512) {
    (&xh[0][0][0])[i] = 0; (&xl[0][0][0])[i] = 0;
  }
  // msg preload (shared, hi/lo): 32 rows x 64 = 2048 elems / 512 thr = 4 each
  {
    int idx = tid * 4, rr = idx >> 6, cc = idx & 63;
    floatx4 v0 = *(const floatx4*)(msg + (size_t)(row0 + rr)*64 + cc);
    #pragma unroll
    for (int j = 0; j < 4; ++j) {
      BfPair p0 = split2(v0[j]);
      msgb[rr][cc + j] = p0.h;  msgl[rr][cc + j] = p0.l;
    }
  }
  // init state: one wave suffices (ordered by the barrier below)
  if (wv == 0) {
    #pragma unroll
    for (int g = 0; g < NG; ++g) {
      floatx4 v = *(const floatx4*)(st0 + (size_t)(row0 + g*16 + ln)*16 + 4*q);
      ushort4v h4, l4;
      #pragma unroll
      for (int e = 0; e < 4; ++e) { BfPair p = split2(v[e]); h4[e] = p.h; l4[e] = p.l; }
      *(ushort4v*)&xh[g][ln][4*q] = h4;
      *(ushort4v*)&xl[g][ln][4*q] = l4;
    }
  }
  __syncthreads();   // msgb/msgl + state + zero-pads ready
  // round-0 word+rinfo: every wave writes the full (identical) set so its own
  // L1 reads are covered without another barrier (benign identical-value race)
  if (lane < NG*16) {
    int g = lane >> 4, n = lane & 15, rrow = lane;
    int s = c_sched[0];
    BfPair i1p = split2(c_shift[0] / 25.0f);
    #pragma unroll
    for (int j = 0; j < 4; ++j) {
      xh[g][n][16+j] = msgb[rrow][4*s+j];
      xl[g][n][16+j] = msgl[rrow][4*s+j];
    }
    xh[g][n][20] = 0;     xl[g][n][20] = 0;   // round 0: i/64 = 0
    xh[g][n][21] = i1p.h; xl[g][n][21] = i1p.l;
  }

  #pragma unroll 1
  for (int r = 0; r < 64; ++r) {
    // -------- Layer 1: x @ W1 -> h1 (own 32-feature slice, both groups) ----
    floatx4 bb1[TT];
    bf16x8  a1[TT];
    const unsigned short* p1 = P1 + ((size_t)(r*16 + TT*wv)*64 + lane)*8;
    #pragma unroll
    for (int tt = 0; tt < TT; ++tt) {
      a1[tt]  = *(const bf16x8*)(p1 + (size_t)tt*512);
      bb1[tt] = *(const floatx4*)(b1 + r*256 + (TT*wv + tt)*16 + 4*q);
    }
    bf16x8 bxh[NG], bxl[NG];
    #pragma unroll
    for (int g = 0; g < NG; ++g) {
      bxh[g] = *(const bf16x8*)&xh[g][ln][8*q];
      bxl[g] = *(const bf16x8*)&xl[g][ln][8*q];
    }
    #pragma unroll
    for (int tt = 0; tt < TT; ++tt) {
      int f0 = (TT*wv + tt)*16 + 4*q;
      #pragma unroll
      for (int g = 0; g < NG; ++g) {
        floatx4 acc = bb1[tt];
        acc = mfma16(a1[tt], bxl[g], acc);
        acc = mfma16(a1[tt], bxh[g], acc);
        ushort4v h4;
        #pragma unroll
        for (int e = 0; e < 4; ++e) h4[e] = bfbits((__bf16)gelu_f(acc[e]));
        *(ushort4v*)&hA[g][ln][f0] = h4;
      }
    }
    __syncthreads();                       // (B) h1 ready; hB free

    // -------- Layer 2: h1 @ W2 -> h2 (own slice, both groups) --------
    // a3/bb3 only on the two L3 waves; latency hides under L2 compute.
    bf16x8 a3[8]; floatx4 bb3;
    if (wv < 2) {
      const unsigned short* p3 = P3 + ((size_t)(r*8)*64 + lane)*8;
      #pragma unroll
      for (int c = 0; c < 8; ++c) a3[c] = *(const bf16x8*)(p3 + (size_t)c*512);
      bb3 = *(const floatx4*)(b3 + r*16 + 4*q);
    }
    floatx4 bb2[TT];
    #pragma unroll
    for (int tt = 0; tt < TT; ++tt)
      bb2[tt] = *(const floatx4*)(b2 + r*256 + (TT*wv + tt)*16 + 4*q);

    bf16x8 Bf[NG][8];
    #pragma unroll
    for (int g = 0; g < NG; ++g)
      #pragma unroll
      for (int c = 0; c < 8; ++c) Bf[g][c] = *(const bf16x8*)&hA[g][ln][32*c + 8*q];

    const unsigned short* p2 = P2 + ((size_t)((r*16 + TT*wv)*8)*64 + lane)*8;
    #pragma unroll
    for (int tt = 0; tt < TT; ++tt) {
      bf16x8 a2[8];
      #pragma unroll
      for (int c = 0; c < 8; ++c)
        a2[c] = *(const bf16x8*)(p2 + (size_t)(tt*8 + c)*512);
      int f0 = (TT*wv + tt)*16 + 4*q;
      #pragma unroll
      for (int g = 0; g < NG; ++g) {
        floatx4 acc = bb2[tt];
        #pragma unroll
        for (int c = 0; c < 8; ++c) acc = mfma16(a2[c], Bf[g][c], acc);
        ushort4v h4;
        #pragma unroll
        for (int e = 0; e < 4; ++e) h4[e] = bfbits((__bf16)gelu_f(acc[e]));
        *(ushort4v*)&hB[g][ln][f0] = h4;
      }
    }
    __syncthreads();                       // (C) h2 ready

    // -------- Layer 3 (distributed: wave g computes group g) --------
    if (wv < 2) {
      const int g = wv;
      floatx4 s = bb3;
      #pragma unroll
      for (int c = 0; c < 8; ++c) {
        bf16x8 bh = *(const bf16x8*)&hB[g][ln][32*c + 8*q];
        s = mfma16(a3[c], bh, s);
      }
      if (r == 63) {
        *(floatx4*)(out + (size_t)(row0 + g*16 + ln)*16 + 4*q) = s;
      } else {
        ushort4v h4, l4;
        #pragma unroll
        for (int e = 0; e < 4; ++e) { BfPair p = split2(s[e]); h4[e] = p.h; l4[e] = p.l; }
        *(ushort4v*)&xh[g][ln][4*q] = h4;
        *(ushort4v*)&xl[g][ln][4*q] = l4;
      }
    }
    // word + rinfo for next round: wave 2 only (published by barrier D)
    if (wv == 2 && lane < NG*16 && r < 63) {
      int g = lane >> 4, n = lane & 15, rrow = lane;
      int sc = c_sched[r+1];
      float i0 = (float)(r+1) * 0.015625f;   // exact in bf16
      BfPair i1p = split2(c_shift[r+1] / 25.0f);
      #pragma unroll
      for (int j = 0; j < 4; ++j) {
        xh[g][n][16+j] = msgb[rrow][4*sc+j];
        xl[g][n][16+j] = msgl[rrow][4*sc+j];
      }
      xh[g][n][20] = bfbits((__bf16)i0); xl[g][n][20] = 0;
      xh[g][n][21] = i1p.h;              xl[g][n][21] = i1p.l;
    }
    if (r < 63) __syncthreads();           // (D) x ready for next L1
  }
}

// ---------------------------------------------------------------------------
extern "C" void kernel_launch(void* const* d_in, const int* in_sizes, int n_in,
                              void* d_out, int out_size, void* d_ws, size_t ws_size,
                              hipStream_t stream) {
  const float* msg = (const float*)d_in[0];
  const float* st0 = (const float*)d_in[1];
  const float* W1  = (const float*)d_in[2];
  const float* b1  = (const float*)d_in[3];
  const float* W2  = (const float*)d_in[4];
  const float* b2  = (const float*)d_in[5];
  const float* W3  = (const float*)d_in[6];
  const float* b3  = (const float*)d_in[7];
  float* out = (float*)d_out;
  (void)in_sizes; (void)n_in; (void)out_size; (void)ws_size;

  unsigned short* P = (unsigned short*)d_ws;
  const int totalGroups = N1G + N2G + N3G;   // 622592
  pack_w<<<(totalGroups + 255) / 256, 256, 0, stream>>>(W1, W2, W3, P);
  md5_main<<<512, 512, 0, stream>>>(msg, st0, b1, b2, b3, P, out);
}

// Round 4
// 432.589 us; speedup vs baseline: 2.6266x; 1.3641x over previous
//
#include <hip/hip_runtime.h>
#include <stdint.h>

// ---------------------------------------------------------------------------
// MD5Surrogate: 64-round scan of 3-layer MLP (22->256->256->16), B=16384.
// fp32 in/out. R14 = R13 (distributed L3) with the spill fixed:
//  R13 loaded a3/bb3 under `if (wv<2)` in the L2 phase and used them after
//  barrier C -> conditionally-defined cross-barrier live range -> allocator
//  spilled a3 every round (WRITE_SIZE 1MB -> 310MB, dur 590us).
//  R14 loads a3/bb3 INSIDE the L3 branch, right before use: live range is
//  ~20 instrs, no cross-barrier liveness, no spill. The 8 a3 loads (L2-hit)
//  issue alongside the 8 hB ds_reads (separate vmcnt/lgkmcnt) -> ~300cy
//  exposed per round (~8us total), vs ~110us of spill cost removed.
// Distributed L3 (from R13): wave0 -> group0, wave1 -> group1; word scatter
// on wave 2; barrier D publishes x. Removes R11's 8-way-redundant L3
// (-21% MFMA/CU, -39% b128 LDS reads/CU, -6 waves of split2 VALU).
// Structure otherwise: 512 thr, 8 waves, NG=2, TT=2, 2 blk/CU, bf16 hi/lo x,
// A&S 7.1.25 gelu, bias-in-accumulator, a2 loaded per-tt in-loop.
// ---------------------------------------------------------------------------

using bf16x8   = __attribute__((ext_vector_type(8))) __bf16;
using floatx4  = __attribute__((ext_vector_type(4))) float;
using ushort4v = __attribute__((ext_vector_type(4))) unsigned short;

__constant__ int c_sched[64] = {
  0,1,2,3,4,5,6,7,8,9,10,11,12,13,14,15,
  1,6,11,0,5,10,15,4,9,14,3,8,13,2,7,12,
  5,8,11,14,1,4,7,10,13,0,3,6,9,12,15,2,
  0,7,14,5,12,3,10,1,8,15,6,13,4,11,2,9
};
__constant__ float c_shift[64] = {
  7,12,17,22,7,12,17,22,7,12,17,22,7,12,17,22,
  5,9,14,20,5,9,14,20,5,9,14,20,5,9,14,20,
  4,11,16,23,4,11,16,23,4,11,16,23,4,11,16,23,
  6,10,15,21,6,10,15,21,6,10,15,21,6,10,15,21
};

__device__ __forceinline__ unsigned short bfbits(__bf16 b) {
  union { __bf16 b; unsigned short u; } v; v.b = b; return v.u;
}
// gelu via A&S 7.1.25 (|eps|<=2.5e-5), constants folded, exp2-scaled
__device__ __forceinline__ float gelu_f(float x) {
  float ax = fabsf(x);
  float t  = __builtin_amdgcn_rcpf(__builtin_fmaf(0.33270222f, ax, 1.0f));
  float e  = __builtin_amdgcn_exp2f(x * x * -0.72134752f);
  float poly = t * __builtin_fmaf(t, __builtin_fmaf(t, 0.7478556f, -0.0958798f),
                                  0.3480242f);
  float er = __builtin_fmaf(-poly, e, 1.0f);
  er = copysignf(er, x);
  float hx = 0.5f * x;
  return __builtin_fmaf(hx, er, hx);
}
__device__ __forceinline__ floatx4 mfma16(bf16x8 a, bf16x8 b, floatx4 c) {
  return __builtin_amdgcn_mfma_f32_16x16x32_bf16(a, b, c, 0, 0, 0);
}
struct BfPair { unsigned short h, l; };
__device__ __forceinline__ BfPair split2(float s) {
  __bf16 hb = (__bf16)s;
  __bf16 lb = (__bf16)(s - (float)hb);
  BfPair p; p.h = bfbits(hb); p.l = bfbits(lb); return p;
}

// ---------------------------------------------------------------------------
// Packed-weight layout: fragment = 64 lanes x 8 bf16. A[m][k]: m=lane&15,
// k=8*(lane>>4)+j.  P1 (r*16+t): W1[r][k][16t+m] (k>=22 -> 0)
//                   P2 ((r*16+t)*8+c): W2[r][32c+k'][16t+m]
//                   P3 (r*8+c): W3[r][32c+k'][m]
// ---------------------------------------------------------------------------
#define N1G (64*16*64)
#define N2G (64*16*8*64)
#define N3G (64*8*64)

__global__ void pack_w(const float* __restrict__ W1,
                       const float* __restrict__ W2,
                       const float* __restrict__ W3,
                       unsigned short* __restrict__ P) {
  int gid = blockIdx.x * blockDim.x + threadIdx.x;
  if (gid >= N1G + N2G + N3G) return;
  unsigned short v[8];
  unsigned short* dst;
  if (gid < N1G) {
    int lane = gid & 63, t = (gid >> 6) & 15, r = gid >> 10;
    int qq = lane >> 4, mm = lane & 15;
    #pragma unroll
    for (int j = 0; j < 8; ++j) {
      int k = 8*qq + j;
      v[j] = (k < 22) ? bfbits((__bf16)W1[(r*22 + k)*256 + 16*t + mm]) : (unsigned short)0;
    }
    dst = P + (size_t)gid * 8;
  } else if (gid < N1G + N2G) {
    int g = gid - N1G;
    int lane = g & 63, c = (g >> 6) & 7, t = (g >> 9) & 15, r = g >> 13;
    int qq = lane >> 4, mm = lane & 15;
    #pragma unroll
    for (int j = 0; j < 8; ++j) {
      int k = 32*c + 8*qq + j;
      v[j] = bfbits((__bf16)W2[((size_t)r*256 + k)*256 + 16*t + mm]);
    }
    dst = P + (size_t)(N1G + g) * 8;
  } else {
    int g = gid - N1G - N2G;
    int lane = g & 63, c = (g >> 6) & 7, r = g >> 9;
    int qq = lane >> 4, mm = lane & 15;
    #pragma unroll
    for (int j = 0; j < 8; ++j) {
      int k = 32*c + 8*qq + j;
      v[j] = bfbits((__bf16)W3[(r*256 + k)*16 + mm]);
    }
    dst = P + (size_t)(N1G + N2G + g) * 8;
  }
  ushort4v lo = { v[0],v[1],v[2],v[3] }, hi = { v[4],v[5],v[6],v[7] };
  *(ushort4v*)dst = lo;
  *(ushort4v*)(dst + 4) = hi;
}

// ---------------------------------------------------------------------------
#define NG  2    // row-groups per block (32 rows/block)
#define TT  2    // feature sub-tiles per wave (8 waves x 32 features = 256)
#define SXW 36   // x row stride (ushorts)
#define SH 264   // h row stride
#define SM 66    // msg row stride

__global__ __launch_bounds__(512, 4) void md5_main(
    const float* __restrict__ msg,   // (16384,64)
    const float* __restrict__ st0,   // (16384,16)
    const float* __restrict__ b1,    // (64,256)
    const float* __restrict__ b2,    // (64,256)
    const float* __restrict__ b3,    // (64,16)
    const unsigned short* __restrict__ P,
    float* __restrict__ out)         // (16384,16)
{
  __shared__ unsigned short xh[NG][16][SXW], xl[NG][16][SXW];
  __shared__ unsigned short hA[NG][16][SH], hB[NG][16][SH];
  __shared__ unsigned short msgb[NG*16][SM], msgl[NG*16][SM];

  const int tid  = threadIdx.x;
  const int wv   = tid >> 6;        // 0..7
  const int lane = tid & 63;
  const int q    = lane >> 4;
  const int ln   = lane & 15;
  const int row0 = blockIdx.x * (NG*16);

  const unsigned short* P1 = P;
  const unsigned short* P2 = P + (size_t)N1G * 8;
  const unsigned short* P3 = P + (size_t)(N1G + N2G) * 8;

  // zero x buffers once (pad cols 22..35 must stay 0 forever)
  for (int i = tid; i < NG*16*SXW; i += 512) {
    (&xh[0][0][0])[i] = 0; (&xl[0][0][0])[i] = 0;
  }
  // msg preload (shared, hi/lo): 32 rows x 64 = 2048 elems / 512 thr = 4 each
  {
    int idx = tid * 4, rr = idx >> 6, cc = idx & 63;
    floatx4 v0 = *(const floatx4*)(msg + (size_t)(row0 + rr)*64 + cc);
    #pragma unroll
    for (int j = 0; j < 4; ++j) {
      BfPair p0 = split2(v0[j]);
      msgb[rr][cc + j] = p0.h;  msgl[rr][cc + j] = p0.l;
    }
  }
  // init state: one wave suffices (ordered by the barrier below)
  if (wv == 0) {
    #pragma unroll
    for (int g = 0; g < NG; ++g) {
      floatx4 v = *(const floatx4*)(st0 + (size_t)(row0 + g*16 + ln)*16 + 4*q);
      ushort4v h4, l4;
      #pragma unroll
      for (int e = 0; e < 4; ++e) { BfPair p = split2(v[e]); h4[e] = p.h; l4[e] = p.l; }
      *(ushort4v*)&xh[g][ln][4*q] = h4;
      *(ushort4v*)&xl[g][ln][4*q] = l4;
    }
  }
  __syncthreads();   // msgb/msgl + state + zero-pads ready
  // round-0 word+rinfo: every wave writes the full (identical) set so its own
  // L1 reads are covered without another barrier (benign identical-value race)
  if (lane < NG*16) {
    int g = lane >> 4, n = lane & 15, rrow = lane;
    int s = c_sched[0];
    BfPair i1p = split2(c_shift[0] / 25.0f);
    #pragma unroll
    for (int j = 0; j < 4; ++j) {
      xh[g][n][16+j] = msgb[rrow][4*s+j];
      xl[g][n][16+j] = msgl[rrow][4*s+j];
    }
    xh[g][n][20] = 0;     xl[g][n][20] = 0;   // round 0: i/64 = 0
    xh[g][n][21] = i1p.h; xl[g][n][21] = i1p.l;
  }

  #pragma unroll 1
  for (int r = 0; r < 64; ++r) {
    // -------- Layer 1: x @ W1 -> h1 (own 32-feature slice, both groups) ----
    floatx4 bb1[TT];
    bf16x8  a1[TT];
    const unsigned short* p1 = P1 + ((size_t)(r*16 + TT*wv)*64 + lane)*8;
    #pragma unroll
    for (int tt = 0; tt < TT; ++tt) {
      a1[tt]  = *(const bf16x8*)(p1 + (size_t)tt*512);
      bb1[tt] = *(const floatx4*)(b1 + r*256 + (TT*wv + tt)*16 + 4*q);
    }
    bf16x8 bxh[NG], bxl[NG];
    #pragma unroll
    for (int g = 0; g < NG; ++g) {
      bxh[g] = *(const bf16x8*)&xh[g][ln][8*q];
      bxl[g] = *(const bf16x8*)&xl[g][ln][8*q];
    }
    #pragma unroll
    for (int tt = 0; tt < TT; ++tt) {
      int f0 = (TT*wv + tt)*16 + 4*q;
      #pragma unroll
      for (int g = 0; g < NG; ++g) {
        floatx4 acc = bb1[tt];
        acc = mfma16(a1[tt], bxl[g], acc);
        acc = mfma16(a1[tt], bxh[g], acc);
        ushort4v h4;
        #pragma unroll
        for (int e = 0; e < 4; ++e) h4[e] = bfbits((__bf16)gelu_f(acc[e]));
        *(ushort4v*)&hA[g][ln][f0] = h4;
      }
    }
    __syncthreads();                       // (B) h1 ready; hB free

    // -------- Layer 2: h1 @ W2 -> h2 (own slice, both groups) --------
    floatx4 bb2[TT];
    #pragma unroll
    for (int tt = 0; tt < TT; ++tt)
      bb2[tt] = *(const floatx4*)(b2 + r*256 + (TT*wv + tt)*16 + 4*q);

    bf16x8 Bf[NG][8];
    #pragma unroll
    for (int g = 0; g < NG; ++g)
      #pragma unroll
      for (int c = 0; c < 8; ++c) Bf[g][c] = *(const bf16x8*)&hA[g][ln][32*c + 8*q];

    const unsigned short* p2 = P2 + ((size_t)((r*16 + TT*wv)*8)*64 + lane)*8;
    #pragma unroll
    for (int tt = 0; tt < TT; ++tt) {
      bf16x8 a2[8];
      #pragma unroll
      for (int c = 0; c < 8; ++c)
        a2[c] = *(const bf16x8*)(p2 + (size_t)(tt*8 + c)*512);
      int f0 = (TT*wv + tt)*16 + 4*q;
      #pragma unroll
      for (int g = 0; g < NG; ++g) {
        floatx4 acc = bb2[tt];
        #pragma unroll
        for (int c = 0; c < 8; ++c) acc = mfma16(a2[c], Bf[g][c], acc);
        ushort4v h4;
        #pragma unroll
        for (int e = 0; e < 4; ++e) h4[e] = bfbits((__bf16)gelu_f(acc[e]));
        *(ushort4v*)&hB[g][ln][f0] = h4;
      }
    }
    __syncthreads();                       // (C) h2 ready

    // -------- Layer 3 (distributed: wave g computes group g) --------
    // a3/bb3 loaded HERE, inside the branch: short contained live range, no
    // cross-barrier conditional liveness -> no spill (R13's failure mode).
    if (wv < 2) {
      const int g = wv;
      const unsigned short* p3 = P3 + ((size_t)(r*8)*64 + lane)*8;
      bf16x8 a3[8];
      #pragma unroll
      for (int c = 0; c < 8; ++c) a3[c] = *(const bf16x8*)(p3 + (size_t)c*512);
      floatx4 s = *(const floatx4*)(b3 + r*16 + 4*q);
      #pragma unroll
      for (int c = 0; c < 8; ++c) {
        bf16x8 bh = *(const bf16x8*)&hB[g][ln][32*c + 8*q];
        s = mfma16(a3[c], bh, s);
      }
      if (r == 63) {
        *(floatx4*)(out + (size_t)(row0 + g*16 + ln)*16 + 4*q) = s;
      } else {
        ushort4v h4, l4;
        #pragma unroll
        for (int e = 0; e < 4; ++e) { BfPair p = split2(s[e]); h4[e] = p.h; l4[e] = p.l; }
        *(ushort4v*)&xh[g][ln][4*q] = h4;
        *(ushort4v*)&xl[g][ln][4*q] = l4;
      }
    }
    // word + rinfo for next round: wave 2 only (published by barrier D)
    if (wv == 2 && lane < NG*16 && r < 63) {
      int g = lane >> 4, n = lane & 15, rrow = lane;
      int sc = c_sched[r+1];
      float i0 = (float)(r+1) * 0.015625f;   // exact in bf16
      BfPair i1p = split2(c_shift[r+1] / 25.0f);
      #pragma unroll
      for (int j = 0; j < 4; ++j) {
        xh[g][n][16+j] = msgb[rrow][4*sc+j];
        xl[g][n][16+j] = msgl[rrow][4*sc+j];
      }
      xh[g][n][20] = bfbits((__bf16)i0); xl[g][n][20] = 0;
      xh[g][n][21] = i1p.h;              xl[g][n][21] = i1p.l;
    }
    if (r < 63) __syncthreads();           // (D) x ready for next L1
  }
}

// ---------------------------------------------------------------------------
extern "C" void kernel_launch(void* const* d_in, const int* in_sizes, int n_in,
                              void* d_out, int out_size, void* d_ws, size_t ws_size,
                              hipStream_t stream) {
  const float* msg = (const float*)d_in[0];
  const float* st0 = (const float*)d_in[1];
  const float* W1  = (const float*)d_in[2];
  const float* b1  = (const float*)d_in[3];
  const float* W2  = (const float*)d_in[4];
  const float* b2  = (const float*)d_in[5];
  const float* W3  = (const float*)d_in[6];
  const float* b3  = (const float*)d_in[7];
  float* out = (float*)d_out;
  (void)in_sizes; (void)n_in; (void)out_size; (void)ws_size;

  unsigned short* P = (unsigned short*)d_ws;
  const int totalGroups = N1G + N2G + N3G;   // 622592
  pack_w<<<(totalGroups + 255) / 256, 256, 0, stream>>>(W1, W2, W3, P);
  md5_main<<<512, 512, 0, stream>>>(msg, st0, b1, b2, b3, P, out);
}